// Round 4
// baseline (480.026 us; speedup 1.0000x reference)
//
#include <hip/hip_runtime.h>
#include <float.h>
#include <stdint.h>

// MimiEuclideanCodebook: argmin_k ||x_n - e_k||^2 then gather e_k.
// R4: R3 with the k-tile partial-overwrite bug fixed — top-2 state is held in
// registers across the 4 k-tiles of each k-split and written to p4 ONCE.
// fp16 split-precision MFMA GEMM (virtual K=768: xh*eh + xl*eh + xh*el),
// BK=64 stages, XOR-swizzled LDS (conflict-free b128 fragment reads),
// k-split=4, fused prep, exact-fp32 repair for rows with approx gap < DELTA.

#define EPSILON 1e-5f
#define DELTA   1e-2f

constexpr int D     = 256;
constexpr int K_TOT = 2048;

typedef _Float16 half8v __attribute__((ext_vector_type(8)));
typedef _Float16 half4v __attribute__((ext_vector_type(4)));
typedef float    f32x4  __attribute__((ext_vector_type(4)));

// ---------------- fused prep: xc (half+residual), ec, esq, counter ----------------
__global__ void prep_kernel(const float* __restrict__ x,
                            const float* __restrict__ es,
                            const float* __restrict__ usage,
                            _Float16* __restrict__ xc,
                            _Float16* __restrict__ ec,
                            float* __restrict__ esq,
                            int* __restrict__ counter, int NB) {
  const int bx   = blockIdx.x;
  const int t    = threadIdx.x;
  const int wid  = t >> 6;
  const int lane = t & 63;
  if (bx < NB) {                       // x rows: half + residual split
    const int n = bx * 4 + wid;
    const float4 v = *(const float4*)(x + (size_t)n * D + lane * 4);
    half4v h, lo;
    h.x = (_Float16)v.x; lo.x = (_Float16)(v.x - (float)h.x);
    h.y = (_Float16)v.y; lo.y = (_Float16)(v.y - (float)h.y);
    h.z = (_Float16)v.z; lo.z = (_Float16)(v.z - (float)h.z);
    h.w = (_Float16)v.w; lo.w = (_Float16)(v.w - (float)h.w);
    *(half4v*)(xc + (size_t)n * 512 + lane * 4)       = h;
    *(half4v*)(xc + (size_t)n * 512 + 256 + lane * 4) = lo;
  } else if (bx < NB + K_TOT / 4) {    // e rows: divide, split, and esq
    const int k = (bx - NB) * 4 + wid;
    const float u = fmaxf(usage[k], EPSILON);
    const float4 v = *(const float4*)(es + (size_t)k * D + lane * 4);
    float4 e;
    e.x = v.x / u; e.y = v.y / u; e.z = v.z / u; e.w = v.w / u;  // exact div
    half4v h, lo;
    h.x = (_Float16)e.x; lo.x = (_Float16)(e.x - (float)h.x);
    h.y = (_Float16)e.y; lo.y = (_Float16)(e.y - (float)h.y);
    h.z = (_Float16)e.z; lo.z = (_Float16)(e.z - (float)h.z);
    h.w = (_Float16)e.w; lo.w = (_Float16)(e.w - (float)h.w);
    *(half4v*)(ec + (size_t)k * 512 + lane * 4)       = h;
    *(half4v*)(ec + (size_t)k * 512 + 256 + lane * 4) = lo;
    float s = e.x * e.x + e.y * e.y + e.z * e.z + e.w * e.w;
    #pragma unroll
    for (int m = 1; m < 64; m <<= 1) s += __shfl_xor(s, m, 64);
    if (lane == 0) esq[k] = s;
  } else {
    if (t == 0) *counter = 0;
  }
}

// ---------------- MFMA distance GEMM + running top-2 ----------------
// Block tile 128(n) x 128(k); 4 waves (wn,wk in 2x2), each 64x64 with 4x4
// 16x16x32 accs. Grid (4 k-splits, N/128); each block loops kt=0..3 over the
// 128-wide k-tiles of its 512-wide split, maintaining per-lane running top-2
// in registers; ONE p4 write per (row, kb, wk) at the end.
// Stage s (BK=64) covers 32-chunks ka=2s,2s+1; ka 0-7: xh*eh, 8-15: xl*eh,
// 16-23: xh*el. LDS 16B chunks XOR-swizzled: phys = log ^ (row&7); the
// global_load_lds LDS dst stays lane-contiguous (we permute the GLOBAL src).
__global__ __launch_bounds__(256, 3)
void mm_kernel(const _Float16* __restrict__ xc, const _Float16* __restrict__ ec,
               const float* __restrict__ esq, float4* __restrict__ p4, int N) {
  __shared__ __align__(16) _Float16 sA[128 * 64];
  __shared__ __align__(16) _Float16 sB[128 * 64];
  const int t    = threadIdx.x;
  const int lane = t & 63;
  const int q    = lane >> 4;
  const int l7   = lane & 7;
  const int wid  = t >> 6;
  const int wn   = wid >> 1;
  const int wk   = wid & 1;
  const int n0   = blockIdx.y * 128;
  const int kb   = blockIdx.x;          // k-split 0..3
  const int k00  = kb * 512;

  float rd0[4][4], rd1[4][4];
  int   ri0[4][4];
  #pragma unroll
  for (int mi = 0; mi < 4; ++mi)
    #pragma unroll
    for (int r = 0; r < 4; ++r) {
      rd0[mi][r] = FLT_MAX; rd1[mi][r] = FLT_MAX; ri0[mi][r] = 0x7fffffff;
    }

  for (int kt = 0; kt < 4; ++kt) {
    const int k0 = k00 + kt * 128;
    f32x4 acc[4][4] = {};

    for (int s = 0; s < 12; ++s) {
      __syncthreads();
      #pragma unroll
      for (int i = 0; i < 4; ++i) {
        const int p    = i * 256 + t;        // 16B slot 0..1023
        const int row  = p >> 3;
        const int chp  = p & 7;
        const int chl  = chp ^ (row & 7);    // logical chunk this slot holds
        const int ka   = 2 * s + (chl >> 2);
        const int pc   = chl & 3;
        const int acol = (ka < 16) ? ka : ka - 16;  // xh | xl | xh
        const int bcol = (ka < 8)  ? ka : ka - 8;   // eh | eh | el
        __builtin_amdgcn_global_load_lds(
            (const __attribute__((address_space(1))) void*)
                (xc + (size_t)(n0 + row) * 512 + acol * 32 + pc * 8),
            (__attribute__((address_space(3))) void*)&sA[p * 8], 16, 0, 0);
        __builtin_amdgcn_global_load_lds(
            (const __attribute__((address_space(1))) void*)
                (ec + (size_t)(k0 + row) * 512 + bcol * 32 + pc * 8),
            (__attribute__((address_space(3))) void*)&sB[p * 8], 16, 0, 0);
      }
      __syncthreads();

      #pragma unroll
      for (int s2 = 0; s2 < 2; ++s2) {
        const int chA = ((s2 * 4 + q) ^ l7) * 8;   // swizzled halfword offset
        half8v af[4], bf[4];
        #pragma unroll
        for (int mi = 0; mi < 4; ++mi)
          af[mi] = *(const half8v*)&sA[(wn * 64 + mi * 16 + (lane & 15)) * 64 + chA];
        #pragma unroll
        for (int ni = 0; ni < 4; ++ni)
          bf[ni] = *(const half8v*)&sB[(wk * 64 + ni * 16 + (lane & 15)) * 64 + chA];
        #pragma unroll
        for (int mi = 0; mi < 4; ++mi)
          #pragma unroll
          for (int ni = 0; ni < 4; ++ni)
            acc[mi][ni] = __builtin_amdgcn_mfma_f32_16x16x32_f16(
                af[mi], bf[ni], acc[mi][ni], 0, 0, 0);
      }
    }

    // Merge this k-tile's candidates into running top-2 (ascending k ->
    // strict '<' keeps the lowest index on ties == argmin first-index).
    #pragma unroll
    for (int ni = 0; ni < 4; ++ni) {
      const int   kc = k0 + wk * 64 + ni * 16 + (lane & 15);
      const float eq = esq[kc];
      #pragma unroll
      for (int mi = 0; mi < 4; ++mi) {
        #pragma unroll
        for (int r = 0; r < 4; ++r) {
          const float d = fmaf(-2.f, acc[mi][ni][r], eq);
          if (d < rd0[mi][r]) {
            rd1[mi][r] = rd0[mi][r]; rd0[mi][r] = d; ri0[mi][r] = kc;
          } else {
            rd1[mi][r] = fminf(rd1[mi][r], d);
          }
        }
      }
    }
  }

  // Cross-lane reduce over the 16 k-columns, one p4 write per row.
  // C layout: col = lane&15, row = (lane>>4)*4 + r within each 16-row block.
  const int pt = kb * 2 + wk;   // partial slot 0..7
  #pragma unroll
  for (int mi = 0; mi < 4; ++mi) {
    #pragma unroll
    for (int r = 0; r < 4; ++r) {
      float d0 = rd0[mi][r], d1 = rd1[mi][r];
      int   i0 = ri0[mi][r];
      #pragma unroll
      for (int off = 1; off < 16; off <<= 1) {
        const float od0 = __shfl_xor(d0, off, 16);
        const int   oi0 = __shfl_xor(i0, off, 16);
        const float od1 = __shfl_xor(d1, off, 16);
        if (od0 < d0 || (od0 == d0 && oi0 < i0)) {
          d1 = fminf(d0, od1); d0 = od0; i0 = oi0;
        } else {
          d1 = fminf(d1, od0);
        }
      }
      if ((lane & 15) == mi * 4 + r) {
        const int n = n0 + wn * 64 + mi * 16 + (lane >> 4) * 4 + r;
        p4[(size_t)n * 8 + pt] = make_float4(d0, __int_as_float(i0), d1, 0.f);
      }
    }
  }
}

// ---------------- combine partials + gather + flag ----------------
__global__ void combine_kernel(const float4* __restrict__ p4,
                               const float* __restrict__ es,
                               const float* __restrict__ usage,
                               float* __restrict__ out_q,
                               float* __restrict__ out_i,
                               int* __restrict__ list,
                               int* __restrict__ counter, int N) {
  const int wid  = threadIdx.x >> 6;
  const int lane = threadIdx.x & 63;
  const int n    = blockIdx.x * 4 + wid;

  float d0 = FLT_MAX, d1 = FLT_MAX;
  int   i0 = 0x7fffffff;
  if (lane < 8) {
    const float4 pv = p4[(size_t)n * 8 + lane];
    d0 = pv.x; i0 = __float_as_int(pv.y); d1 = pv.z;
  }
  #pragma unroll
  for (int off = 1; off < 8; off <<= 1) {
    const float od0 = __shfl_xor(d0, off, 8);
    const int   oi0 = __shfl_xor(i0, off, 8);
    const float od1 = __shfl_xor(d1, off, 8);
    if (od0 < d0 || (od0 == d0 && oi0 < i0)) {
      d1 = fminf(d0, od1); d0 = od0; i0 = oi0;
    } else {
      d1 = fminf(d1, od0);
    }
  }
  const int   idx = __shfl(i0, 0, 64);
  const float g0  = __shfl(d0, 0, 64);
  const float g1  = __shfl(d1, 0, 64);

  const float u = fmaxf(usage[idx], EPSILON);
  const float4 e = *(const float4*)(es + (size_t)idx * D + lane * 4);
  float4 qv;
  qv.x = e.x / u; qv.y = e.y / u; qv.z = e.z / u; qv.w = e.w / u;  // exact div
  *(float4*)(out_q + (size_t)n * D + lane * 4) = qv;
  if (lane == 0) {
    out_i[n] = (float)idx;
    if (g1 - g0 < DELTA) {
      const int pos = atomicAdd(counter, 1);
      list[pos] = n;
    }
  }
}

// ---------------- exact fp32 repair for flagged rows ----------------
__global__ void repair_kernel(const float* __restrict__ x,
                              const float* __restrict__ es,
                              const float* __restrict__ usage,
                              const float* __restrict__ esq,
                              const int* __restrict__ list,
                              const int* __restrict__ counter,
                              float* __restrict__ out_q,
                              float* __restrict__ out_i, int N) {
  __shared__ float xs[256];
  __shared__ float swd[4];
  __shared__ int   swi[4];
  __shared__ int   sbi;
  const int t    = threadIdx.x;
  const int w    = t >> 6;
  const int lane = t & 63;
  const int cnt  = *counter;

  for (int j = blockIdx.x; j < cnt; j += 1024) {
    const int n = list[j];
    __syncthreads();
    xs[t] = x[(size_t)n * D + t];
    __syncthreads();
    const float4 xv = *(const float4*)&xs[lane * 4];

    float bd = FLT_MAX;
    int   bi = 0x7fffffff;
    for (int kk = 0; kk < K_TOT / 4; ++kk) {
      const int k = w * (K_TOT / 4) + kk;   // ascending per wave
      const float rs = 1.0f / fmaxf(usage[k], EPSILON);
      const float4 e = *(const float4*)(es + (size_t)k * D + lane * 4);
      float pd = xv.x * (e.x * rs);
      pd = fmaf(xv.y, e.y * rs, pd);
      pd = fmaf(xv.z, e.z * rs, pd);
      pd = fmaf(xv.w, e.w * rs, pd);
      #pragma unroll
      for (int off = 1; off < 64; off <<= 1) pd += __shfl_xor(pd, off, 64);
      const float dst = fmaf(-2.f, pd, esq[k]);
      if (dst < bd) { bd = dst; bi = k; }
    }
    if (lane == 0) { swd[w] = bd; swi[w] = bi; }
    __syncthreads();
    if (t == 0) {
      float gd = swd[0]; int gi = swi[0];
      #pragma unroll
      for (int p = 1; p < 4; ++p) {
        if (swd[p] < gd || (swd[p] == gd && swi[p] < gi)) {
          gd = swd[p]; gi = swi[p];
        }
      }
      sbi = gi;
    }
    __syncthreads();
    const int idx = sbi;
    const float u = fmaxf(usage[idx], EPSILON);
    out_q[(size_t)n * D + t] = es[(size_t)idx * D + t] / u;
    if (t == 0) out_i[n] = (float)idx;
  }
}

// ---------------- fallback path (R1, fp32 vector) ----------------
constexpr int TN = 128;
constexpr int DC = 32;
constexpr int KS = 2;
constexpr int RS = 196;

__global__ void esq_kernel(const float* __restrict__ es,
                           const float* __restrict__ usage,
                           float* __restrict__ esq) {
  const int lane = threadIdx.x & 63;
  const int w    = threadIdx.x >> 6;
  const int k    = blockIdx.x * 4 + w;
  const float u  = fmaxf(usage[k], EPSILON);
  const float4 e = *(const float4*)(es + (size_t)k * D + lane * 4);
  const float a = e.x / u, b = e.y / u, c = e.z / u, d = e.w / u;
  float s = a * a + b * b + c * c + d * d;
  #pragma unroll
  for (int m = 1; m < 64; m <<= 1) s += __shfl_xor(s, m, 64);
  if (lane == 0) esq[k] = s;
}

__global__ __launch_bounds__(256, 2)
void dist_kernel(const float* __restrict__ x,
                 const float* __restrict__ es,
                 const float* __restrict__ usage,
                 const float* __restrict__ esq,
                 float* __restrict__ bestd,
                 int* __restrict__ besti, int N) {
  __shared__ float smX[DC * RS];
  __shared__ float smE[DC * RS];
  const int t    = threadIdx.x;
  const int tx   = t & 15;
  const int ty   = t >> 4;
  const int n0   = blockIdx.x * TN;
  const int half = blockIdx.y;

  float best[8];
  int   bidx[8];
  #pragma unroll
  for (int i = 0; i < 8; ++i) { best[i] = FLT_MAX; bidx[i] = 0; }

  for (int kt = 0; kt < (K_TOT / KS) / 128; ++kt) {
    const int k0 = half * (K_TOT / KS) + kt * 128;
    float acc[8][8];
    #pragma unroll
    for (int i = 0; i < 8; ++i)
      #pragma unroll
      for (int j = 0; j < 8; ++j) acc[i][j] = 0.f;

    for (int dc = 0; dc < D; dc += DC) {
      __syncthreads();
      #pragma unroll
      for (int i = 0; i < 4; ++i) {
        const int f    = i * 256 + t;
        const int row  = f >> 3;
        const int c4   = f & 7;
        const int pcol = row + ((row >> 3) << 2);
        const float4 xv =
            *(const float4*)(x + (size_t)(n0 + row) * D + dc + c4 * 4);
        smX[(c4 * 4 + 0) * RS + pcol] = xv.x;
        smX[(c4 * 4 + 1) * RS + pcol] = xv.y;
        smX[(c4 * 4 + 2) * RS + pcol] = xv.z;
        smX[(c4 * 4 + 3) * RS + pcol] = xv.w;
        const int kk = k0 + row;
        const float rs = 1.0f / fmaxf(usage[kk], EPSILON);
        const float4 ev =
            *(const float4*)(es + (size_t)kk * D + dc + c4 * 4);
        smE[(c4 * 4 + 0) * RS + pcol] = ev.x * rs;
        smE[(c4 * 4 + 1) * RS + pcol] = ev.y * rs;
        smE[(c4 * 4 + 2) * RS + pcol] = ev.z * rs;
        smE[(c4 * 4 + 3) * RS + pcol] = ev.w * rs;
      }
      __syncthreads();
      #pragma unroll 4
      for (int d = 0; d < DC; ++d) {
        const float* px = &smX[d * RS + ty * 12];
        const float* pe = &smE[d * RS + tx * 12];
        const float4 xa = *(const float4*)px;
        const float4 xb = *(const float4*)(px + 4);
        const float4 ea = *(const float4*)pe;
        const float4 eb = *(const float4*)(pe + 4);
        const float xr[8] = {xa.x, xa.y, xa.z, xa.w, xb.x, xb.y, xb.z, xb.w};
        const float er[8] = {ea.x, ea.y, ea.z, ea.w, eb.x, eb.y, eb.z, eb.w};
        #pragma unroll
        for (int i = 0; i < 8; ++i)
          #pragma unroll
          for (int jj = 0; jj < 8; ++jj)
            acc[i][jj] = fmaf(xr[i], er[jj], acc[i][jj]);
      }
    }
    #pragma unroll
    for (int jj = 0; jj < 8; ++jj) {
      const int k = k0 + tx * 8 + jj;
      const float eq = esq[k];
      #pragma unroll
      for (int i = 0; i < 8; ++i) {
        const float dst = fmaf(-2.0f, acc[i][jj], eq);
        if (dst < best[i]) { best[i] = dst; bidx[i] = k; }
      }
    }
  }
  __syncthreads();
  float* rd = smX;
  int*   ri = (int*)smE;
  #pragma unroll
  for (int i = 0; i < 8; ++i) {
    const int r = ty * 8 + i;
    rd[tx * TN + r] = best[i];
    ri[tx * TN + r] = bidx[i];
  }
  __syncthreads();
  for (int off = 8; off >= 1; off >>= 1) {
    if (tx < off) {
      #pragma unroll
      for (int i = 0; i < 8; ++i) {
        const int r = ty * 8 + i;
        const float da = rd[tx * TN + r], db = rd[(tx + off) * TN + r];
        const int   ia = ri[tx * TN + r], ib = ri[(tx + off) * TN + r];
        if (db < da || (db == da && ib < ia)) {
          rd[tx * TN + r] = db;
          ri[tx * TN + r] = ib;
        }
      }
    }
    __syncthreads();
  }
  if (tx == 0) {
    #pragma unroll
    for (int i = 0; i < 8; ++i) {
      const int r = ty * 8 + i;
      bestd[(size_t)half * N + n0 + r] = rd[r];
      besti[(size_t)half * N + n0 + r] = ri[r];
    }
  }
}

__global__ void gather_kernel(const float* __restrict__ es,
                              const float* __restrict__ usage,
                              const float* __restrict__ bestd,
                              const int* __restrict__ besti,
                              float* __restrict__ out_q,
                              float* __restrict__ out_i, int N) {
  const int w    = threadIdx.x >> 6;
  const int lane = threadIdx.x & 63;
  const int n    = blockIdx.x * 4 + w;
  const float d0 = bestd[n];
  const float d1 = bestd[(size_t)N + n];
  const int   i0 = besti[n];
  const int   i1 = besti[(size_t)N + n];
  const int idx = (d1 < d0) ? i1 : i0;
  const float u = fmaxf(usage[idx], EPSILON);
  const float4 e = *(const float4*)(es + (size_t)idx * D + lane * 4);
  float4 qv;
  qv.x = e.x / u; qv.y = e.y / u; qv.z = e.z / u; qv.w = e.w / u;
  *(float4*)(out_q + (size_t)n * D + lane * 4) = qv;
  if (lane == 0) out_i[n] = (float)idx;
}

// ---------------- launch ----------------
extern "C" void kernel_launch(void* const* d_in, const int* in_sizes, int n_in,
                              void* d_out, int out_size, void* d_ws, size_t ws_size,
                              hipStream_t stream) {
  const float* x     = (const float*)d_in[0];  // [N, 256]
  const float* es    = (const float*)d_in[1];  // [2048, 256]
  const float* usage = (const float*)d_in[2];  // [2048]
  const int N = in_sizes[0] / D;               // 32768

  float* out_q = (float*)d_out;
  float* out_i = out_q + (size_t)N * D;

  const size_t XB = (size_t)N * 512 * 2;        // xc: 33.5 MB
  const size_t EB = (size_t)K_TOT * 512 * 2;    // ec: 2 MB
  const size_t PB = (size_t)N * 8 * 16;         // p4: 4 MB
  const size_t off_ec   = XB;
  const size_t off_p4   = XB + EB;
  const size_t off_esq  = off_p4 + PB;
  const size_t off_list = off_esq + 8192;
  const size_t off_cnt  = off_list + (size_t)N * 4;
  const size_t NEED     = off_cnt + 16;

  char* wsb = (char*)d_ws;

  if (ws_size >= NEED) {
    _Float16* xc   = (_Float16*)wsb;
    _Float16* ec   = (_Float16*)(wsb + off_ec);
    float4*   p4   = (float4*)(wsb + off_p4);
    float*    esq  = (float*)(wsb + off_esq);
    int*      list = (int*)(wsb + off_list);
    int*      cnt  = (int*)(wsb + off_cnt);

    const int NB = N / 4;
    prep_kernel<<<NB + K_TOT / 4 + 1, 256, 0, stream>>>(x, es, usage, xc, ec,
                                                        esq, cnt, NB);
    mm_kernel<<<dim3(4, N / 128), 256, 0, stream>>>(xc, ec, esq, p4, N);
    combine_kernel<<<N / 4, 256, 0, stream>>>(p4, es, usage, out_q, out_i,
                                              list, cnt, N);
    repair_kernel<<<1024, 256, 0, stream>>>(x, es, usage, esq, list, cnt,
                                            out_q, out_i, N);
  } else {
    float* ws    = (float*)d_ws;
    float* esq   = ws;
    float* bestd = ws + K_TOT;
    int*   besti = (int*)(ws + K_TOT + (size_t)KS * N);
    esq_kernel<<<K_TOT / 4, 256, 0, stream>>>(es, usage, esq);
    dist_kernel<<<dim3(N / TN, KS), 256, 0, stream>>>(x, es, usage, esq,
                                                      bestd, besti, N);
    gather_kernel<<<N / 4, 256, 0, stream>>>(es, usage, bestd, besti,
                                             out_q, out_i, N);
  }
}

// Round 5
// 389.935 us; speedup vs baseline: 1.2310x; 1.2310x over previous
//
#include <hip/hip_runtime.h>
#include <float.h>
#include <stdint.h>

// MimiEuclideanCodebook: argmin_k ||x_n - e_k||^2 then gather e_k.
// R5: R2 grid structure (16 k-blocks x 256 n-blocks, one 128x128 tile per
// block, epilogue straight from acc -> no cross-tile register state, no
// spills) + R4's verified XOR-swizzled BK=64 staging (0 bank conflicts,
// half the barriers of BK=32). fp16 split-precision MFMA (virtual K=768:
// xh*eh + xl*eh + xh*el; error ~1e-5). DELTA 1e-3; repair has 4-wide ILP.

#define EPSILON 1e-5f
#define DELTA   1e-3f

constexpr int D     = 256;
constexpr int K_TOT = 2048;

typedef _Float16 half8v __attribute__((ext_vector_type(8)));
typedef _Float16 half4v __attribute__((ext_vector_type(4)));
typedef float    f32x4  __attribute__((ext_vector_type(4)));

// ---------------- fused prep: xc (half+residual), ec, esq, counter ----------------
__global__ void prep_kernel(const float* __restrict__ x,
                            const float* __restrict__ es,
                            const float* __restrict__ usage,
                            _Float16* __restrict__ xc,
                            _Float16* __restrict__ ec,
                            float* __restrict__ esq,
                            int* __restrict__ counter, int NB) {
  const int bx   = blockIdx.x;
  const int t    = threadIdx.x;
  const int wid  = t >> 6;
  const int lane = t & 63;
  if (bx < NB) {                       // x rows: half + residual split
    const int n = bx * 4 + wid;
    const float4 v = *(const float4*)(x + (size_t)n * D + lane * 4);
    half4v h, lo;
    h.x = (_Float16)v.x; lo.x = (_Float16)(v.x - (float)h.x);
    h.y = (_Float16)v.y; lo.y = (_Float16)(v.y - (float)h.y);
    h.z = (_Float16)v.z; lo.z = (_Float16)(v.z - (float)h.z);
    h.w = (_Float16)v.w; lo.w = (_Float16)(v.w - (float)h.w);
    *(half4v*)(xc + (size_t)n * 512 + lane * 4)       = h;
    *(half4v*)(xc + (size_t)n * 512 + 256 + lane * 4) = lo;
  } else if (bx < NB + K_TOT / 4) {    // e rows: divide, split, and esq
    const int k = (bx - NB) * 4 + wid;
    const float u = fmaxf(usage[k], EPSILON);
    const float4 v = *(const float4*)(es + (size_t)k * D + lane * 4);
    float4 e;
    e.x = v.x / u; e.y = v.y / u; e.z = v.z / u; e.w = v.w / u;  // exact div
    half4v h, lo;
    h.x = (_Float16)e.x; lo.x = (_Float16)(e.x - (float)h.x);
    h.y = (_Float16)e.y; lo.y = (_Float16)(e.y - (float)h.y);
    h.z = (_Float16)e.z; lo.z = (_Float16)(e.z - (float)h.z);
    h.w = (_Float16)e.w; lo.w = (_Float16)(e.w - (float)h.w);
    *(half4v*)(ec + (size_t)k * 512 + lane * 4)       = h;
    *(half4v*)(ec + (size_t)k * 512 + 256 + lane * 4) = lo;
    float s = e.x * e.x + e.y * e.y + e.z * e.z + e.w * e.w;
    #pragma unroll
    for (int m = 1; m < 64; m <<= 1) s += __shfl_xor(s, m, 64);
    if (lane == 0) esq[k] = s;
  } else {
    if (t == 0) *counter = 0;
  }
}

// ---------------- MFMA distance GEMM + per-tile top-2 ----------------
// Block tile 128(n) x 128(k); 4 waves (wn,wk in 2x2), each 64x64 with 4x4
// 16x16x32 f16 accs. Grid (16 k-blocks, N/128 n-blocks) - x-fastest so the 16
// blocks sharing an A-tile launch adjacently (L2 reuse). Virtual K=768 in 12
// BK=64 stages; stage s covers 32-chunks ka=2s,2s+1; ka 0-7: xh*eh,
// 8-15: xl*eh, 16-23: xh*el. LDS 16B chunks XOR-swizzled: phys = log^(row&7);
// global_load_lds LDS dst stays lane-contiguous (the GLOBAL src is permuted).
__global__ __launch_bounds__(256)
void mm_kernel(const _Float16* __restrict__ xc, const _Float16* __restrict__ ec,
               const float* __restrict__ esq, float4* __restrict__ p4, int N) {
  __shared__ __align__(16) _Float16 sA[128 * 64];
  __shared__ __align__(16) _Float16 sB[128 * 64];
  const int t    = threadIdx.x;
  const int lane = t & 63;
  const int q    = lane >> 4;
  const int l7   = lane & 7;
  const int wid  = t >> 6;
  const int wn   = wid >> 1;
  const int wk   = wid & 1;
  const int n0   = blockIdx.y * 128;
  const int k0   = blockIdx.x * 128;

  f32x4 acc[4][4] = {};

  for (int s = 0; s < 12; ++s) {
    __syncthreads();
    #pragma unroll
    for (int i = 0; i < 4; ++i) {
      const int p    = i * 256 + t;        // 16B slot 0..1023
      const int row  = p >> 3;
      const int chp  = p & 7;
      const int chl  = chp ^ (row & 7);    // logical chunk this slot holds
      const int ka   = 2 * s + (chl >> 2);
      const int pc   = chl & 3;
      const int acol = (ka < 16) ? ka : ka - 16;  // xh | xl | xh
      const int bcol = (ka < 8)  ? ka : ka - 8;   // eh | eh | el
      __builtin_amdgcn_global_load_lds(
          (const __attribute__((address_space(1))) void*)
              (xc + (size_t)(n0 + row) * 512 + acol * 32 + pc * 8),
          (__attribute__((address_space(3))) void*)&sA[p * 8], 16, 0, 0);
      __builtin_amdgcn_global_load_lds(
          (const __attribute__((address_space(1))) void*)
              (ec + (size_t)(k0 + row) * 512 + bcol * 32 + pc * 8),
          (__attribute__((address_space(3))) void*)&sB[p * 8], 16, 0, 0);
    }
    __syncthreads();

    #pragma unroll
    for (int s2 = 0; s2 < 2; ++s2) {
      const int chA = ((s2 * 4 + q) ^ l7) * 8;   // swizzled halfword offset
      half8v af[4], bf[4];
      #pragma unroll
      for (int mi = 0; mi < 4; ++mi)
        af[mi] = *(const half8v*)&sA[(wn * 64 + mi * 16 + (lane & 15)) * 64 + chA];
      #pragma unroll
      for (int ni = 0; ni < 4; ++ni)
        bf[ni] = *(const half8v*)&sB[(wk * 64 + ni * 16 + (lane & 15)) * 64 + chA];
      #pragma unroll
      for (int mi = 0; mi < 4; ++mi)
        #pragma unroll
        for (int ni = 0; ni < 4; ++ni)
          acc[mi][ni] = __builtin_amdgcn_mfma_f32_16x16x32_f16(
              af[mi], bf[ni], acc[mi][ni], 0, 0, 0);
    }
  }

  // Epilogue: dist = esq - 2*dot; top-2 over this wave's 64 k cols.
  // C layout: col = lane&15, row = (lane>>4)*4 + r within each 16-row block.
  float eqv[4];
  int   kc[4];
  #pragma unroll
  for (int ni = 0; ni < 4; ++ni) {
    kc[ni]  = k0 + wk * 64 + ni * 16 + (lane & 15);
    eqv[ni] = esq[kc[ni]];
  }
  const int pt = blockIdx.x * 2 + wk;   // partial slot 0..31, ascending in k
  #pragma unroll
  for (int mi = 0; mi < 4; ++mi) {
    #pragma unroll
    for (int r = 0; r < 4; ++r) {
      float d0 = FLT_MAX, d1 = FLT_MAX;
      int   i0 = 0x7fffffff;
      #pragma unroll
      for (int ni = 0; ni < 4; ++ni) {
        const float d = fmaf(-2.f, acc[mi][ni][r], eqv[ni]);
        if (d < d0) { d1 = d0; d0 = d; i0 = kc[ni]; }
        else if (d < d1) { d1 = d; }
      }
      #pragma unroll
      for (int off = 1; off < 16; off <<= 1) {
        const float od0 = __shfl_xor(d0, off, 16);
        const int   oi0 = __shfl_xor(i0, off, 16);
        const float od1 = __shfl_xor(d1, off, 16);
        if (od0 < d0 || (od0 == d0 && oi0 < i0)) {
          d1 = fminf(d0, od1); d0 = od0; i0 = oi0;
        } else {
          d1 = fminf(d1, od0);
        }
      }
      if ((lane & 15) == mi * 4 + r) {
        const int n = n0 + wn * 64 + mi * 16 + (lane >> 4) * 4 + r;
        p4[(size_t)n * 32 + pt] = make_float4(d0, __int_as_float(i0), d1, 0.f);
      }
    }
  }
}

// ---------------- combine partials + gather + flag ----------------
__global__ void combine_kernel(const float4* __restrict__ p4,
                               const float* __restrict__ es,
                               const float* __restrict__ usage,
                               float* __restrict__ out_q,
                               float* __restrict__ out_i,
                               int* __restrict__ list,
                               int* __restrict__ counter, int N) {
  const int wid  = threadIdx.x >> 6;
  const int lane = threadIdx.x & 63;
  const int n    = blockIdx.x * 4 + wid;

  float d0 = FLT_MAX, d1 = FLT_MAX;
  int   i0 = 0x7fffffff;
  if (lane < 32) {
    const float4 pv = p4[(size_t)n * 32 + lane];
    d0 = pv.x; i0 = __float_as_int(pv.y); d1 = pv.z;
  }
  #pragma unroll
  for (int off = 1; off < 64; off <<= 1) {
    const float od0 = __shfl_xor(d0, off, 64);
    const int   oi0 = __shfl_xor(i0, off, 64);
    const float od1 = __shfl_xor(d1, off, 64);
    if (od0 < d0 || (od0 == d0 && oi0 < i0)) {
      d1 = fminf(d0, od1); d0 = od0; i0 = oi0;
    } else {
      d1 = fminf(d1, od0);
    }
  }
  const int idx = i0;
  const float u = fmaxf(usage[idx], EPSILON);
  const float4 e = *(const float4*)(es + (size_t)idx * D + lane * 4);
  float4 qv;
  qv.x = e.x / u; qv.y = e.y / u; qv.z = e.z / u; qv.w = e.w / u;  // exact div
  *(float4*)(out_q + (size_t)n * D + lane * 4) = qv;
  if (lane == 0) {
    out_i[n] = (float)idx;
    if (d1 - d0 < DELTA) {
      const int pos = atomicAdd(counter, 1);
      list[pos] = n;
    }
  }
}

// ---------------- exact fp32 repair for flagged rows (4-wide ILP) ----------------
__global__ void repair_kernel(const float* __restrict__ x,
                              const float* __restrict__ es,
                              const float* __restrict__ usage,
                              const float* __restrict__ esq,
                              const int* __restrict__ list,
                              const int* __restrict__ counter,
                              float* __restrict__ out_q,
                              float* __restrict__ out_i, int N) {
  __shared__ float xs[256];
  __shared__ float swd[4];
  __shared__ int   swi[4];
  __shared__ int   sbi;
  const int t    = threadIdx.x;
  const int w    = t >> 6;
  const int lane = t & 63;
  const int cnt  = *counter;

  for (int j = blockIdx.x; j < cnt; j += 1024) {
    const int n = list[j];
    __syncthreads();
    xs[t] = x[(size_t)n * D + t];
    __syncthreads();
    const float4 xv = *(const float4*)&xs[lane * 4];

    float bd = FLT_MAX;
    int   bi = 0x7fffffff;
    for (int kk = 0; kk < K_TOT / 4; kk += 4) {
      const int kbase = w * (K_TOT / 4) + kk;   // ascending per wave
      float pd[4];
      #pragma unroll
      for (int j2 = 0; j2 < 4; ++j2) {
        const int k = kbase + j2;
        const float rs = 1.0f / fmaxf(usage[k], EPSILON);
        const float4 e = *(const float4*)(es + (size_t)k * D + lane * 4);
        float p = xv.x * (e.x * rs);
        p = fmaf(xv.y, e.y * rs, p);
        p = fmaf(xv.z, e.z * rs, p);
        pd[j2] = fmaf(xv.w, e.w * rs, p);
      }
      #pragma unroll
      for (int off = 1; off < 64; off <<= 1) {   // 4 independent chains
        pd[0] += __shfl_xor(pd[0], off, 64);
        pd[1] += __shfl_xor(pd[1], off, 64);
        pd[2] += __shfl_xor(pd[2], off, 64);
        pd[3] += __shfl_xor(pd[3], off, 64);
      }
      #pragma unroll
      for (int j2 = 0; j2 < 4; ++j2) {
        const float dst = fmaf(-2.f, pd[j2], esq[kbase + j2]);
        if (dst < bd) { bd = dst; bi = kbase + j2; }
      }
    }
    if (lane == 0) { swd[w] = bd; swi[w] = bi; }
    __syncthreads();
    if (t == 0) {
      float gd = swd[0]; int gi = swi[0];
      #pragma unroll
      for (int p = 1; p < 4; ++p) {
        if (swd[p] < gd || (swd[p] == gd && swi[p] < gi)) {
          gd = swd[p]; gi = swi[p];
        }
      }
      sbi = gi;
    }
    __syncthreads();
    const int idx = sbi;
    const float u = fmaxf(usage[idx], EPSILON);
    out_q[(size_t)n * D + t] = es[(size_t)idx * D + t] / u;
    if (t == 0) out_i[n] = (float)idx;
  }
}

// ---------------- fallback path (R1, fp32 vector) ----------------
constexpr int TN = 128;
constexpr int DC = 32;
constexpr int KS = 2;
constexpr int RS = 196;

__global__ void esq_kernel(const float* __restrict__ es,
                           const float* __restrict__ usage,
                           float* __restrict__ esq) {
  const int lane = threadIdx.x & 63;
  const int w    = threadIdx.x >> 6;
  const int k    = blockIdx.x * 4 + w;
  const float u  = fmaxf(usage[k], EPSILON);
  const float4 e = *(const float4*)(es + (size_t)k * D + lane * 4);
  const float a = e.x / u, b = e.y / u, c = e.z / u, d = e.w / u;
  float s = a * a + b * b + c * c + d * d;
  #pragma unroll
  for (int m = 1; m < 64; m <<= 1) s += __shfl_xor(s, m, 64);
  if (lane == 0) esq[k] = s;
}

__global__ __launch_bounds__(256, 2)
void dist_kernel(const float* __restrict__ x,
                 const float* __restrict__ es,
                 const float* __restrict__ usage,
                 const float* __restrict__ esq,
                 float* __restrict__ bestd,
                 int* __restrict__ besti, int N) {
  __shared__ float smX[DC * RS];
  __shared__ float smE[DC * RS];
  const int t    = threadIdx.x;
  const int tx   = t & 15;
  const int ty   = t >> 4;
  const int n0   = blockIdx.x * TN;
  const int half = blockIdx.y;

  float best[8];
  int   bidx[8];
  #pragma unroll
  for (int i = 0; i < 8; ++i) { best[i] = FLT_MAX; bidx[i] = 0; }

  for (int kt = 0; kt < (K_TOT / KS) / 128; ++kt) {
    const int k0 = half * (K_TOT / KS) + kt * 128;
    float acc[8][8];
    #pragma unroll
    for (int i = 0; i < 8; ++i)
      #pragma unroll
      for (int j = 0; j < 8; ++j) acc[i][j] = 0.f;

    for (int dc = 0; dc < D; dc += DC) {
      __syncthreads();
      #pragma unroll
      for (int i = 0; i < 4; ++i) {
        const int f    = i * 256 + t;
        const int row  = f >> 3;
        const int c4   = f & 7;
        const int pcol = row + ((row >> 3) << 2);
        const float4 xv =
            *(const float4*)(x + (size_t)(n0 + row) * D + dc + c4 * 4);
        smX[(c4 * 4 + 0) * RS + pcol] = xv.x;
        smX[(c4 * 4 + 1) * RS + pcol] = xv.y;
        smX[(c4 * 4 + 2) * RS + pcol] = xv.z;
        smX[(c4 * 4 + 3) * RS + pcol] = xv.w;
        const int kk = k0 + row;
        const float rs = 1.0f / fmaxf(usage[kk], EPSILON);
        const float4 ev =
            *(const float4*)(es + (size_t)kk * D + dc + c4 * 4);
        smE[(c4 * 4 + 0) * RS + pcol] = ev.x * rs;
        smE[(c4 * 4 + 1) * RS + pcol] = ev.y * rs;
        smE[(c4 * 4 + 2) * RS + pcol] = ev.z * rs;
        smE[(c4 * 4 + 3) * RS + pcol] = ev.w * rs;
      }
      __syncthreads();
      #pragma unroll 4
      for (int d = 0; d < DC; ++d) {
        const float* px = &smX[d * RS + ty * 12];
        const float* pe = &smE[d * RS + tx * 12];
        const float4 xa = *(const float4*)px;
        const float4 xb = *(const float4*)(px + 4);
        const float4 ea = *(const float4*)pe;
        const float4 eb = *(const float4*)(pe + 4);
        const float xr[8] = {xa.x, xa.y, xa.z, xa.w, xb.x, xb.y, xb.z, xb.w};
        const float er[8] = {ea.x, ea.y, ea.z, ea.w, eb.x, eb.y, eb.z, eb.w};
        #pragma unroll
        for (int i = 0; i < 8; ++i)
          #pragma unroll
          for (int jj = 0; jj < 8; ++jj)
            acc[i][jj] = fmaf(xr[i], er[jj], acc[i][jj]);
      }
    }
    #pragma unroll
    for (int jj = 0; jj < 8; ++jj) {
      const int k = k0 + tx * 8 + jj;
      const float eq = esq[k];
      #pragma unroll
      for (int i = 0; i < 8; ++i) {
        const float dst = fmaf(-2.0f, acc[i][jj], eq);
        if (dst < best[i]) { best[i] = dst; bidx[i] = k; }
      }
    }
  }
  __syncthreads();
  float* rd = smX;
  int*   ri = (int*)smE;
  #pragma unroll
  for (int i = 0; i < 8; ++i) {
    const int r = ty * 8 + i;
    rd[tx * TN + r] = best[i];
    ri[tx * TN + r] = bidx[i];
  }
  __syncthreads();
  for (int off = 8; off >= 1; off >>= 1) {
    if (tx < off) {
      #pragma unroll
      for (int i = 0; i < 8; ++i) {
        const int r = ty * 8 + i;
        const float da = rd[tx * TN + r], db = rd[(tx + off) * TN + r];
        const int   ia = ri[tx * TN + r], ib = ri[(tx + off) * TN + r];
        if (db < da || (db == da && ib < ia)) {
          rd[tx * TN + r] = db;
          ri[tx * TN + r] = ib;
        }
      }
    }
    __syncthreads();
  }
  if (tx == 0) {
    #pragma unroll
    for (int i = 0; i < 8; ++i) {
      const int r = ty * 8 + i;
      bestd[(size_t)half * N + n0 + r] = rd[r];
      besti[(size_t)half * N + n0 + r] = ri[r];
    }
  }
}

__global__ void gather_kernel(const float* __restrict__ es,
                              const float* __restrict__ usage,
                              const float* __restrict__ bestd,
                              const int* __restrict__ besti,
                              float* __restrict__ out_q,
                              float* __restrict__ out_i, int N) {
  const int w    = threadIdx.x >> 6;
  const int lane = threadIdx.x & 63;
  const int n    = blockIdx.x * 4 + w;
  const float d0 = bestd[n];
  const float d1 = bestd[(size_t)N + n];
  const int   i0 = besti[n];
  const int   i1 = besti[(size_t)N + n];
  const int idx = (d1 < d0) ? i1 : i0;
  const float u = fmaxf(usage[idx], EPSILON);
  const float4 e = *(const float4*)(es + (size_t)idx * D + lane * 4);
  float4 qv;
  qv.x = e.x / u; qv.y = e.y / u; qv.z = e.z / u; qv.w = e.w / u;
  *(float4*)(out_q + (size_t)n * D + lane * 4) = qv;
  if (lane == 0) out_i[n] = (float)idx;
}

// ---------------- launch ----------------
extern "C" void kernel_launch(void* const* d_in, const int* in_sizes, int n_in,
                              void* d_out, int out_size, void* d_ws, size_t ws_size,
                              hipStream_t stream) {
  const float* x     = (const float*)d_in[0];  // [N, 256]
  const float* es    = (const float*)d_in[1];  // [2048, 256]
  const float* usage = (const float*)d_in[2];  // [2048]
  const int N = in_sizes[0] / D;               // 32768

  float* out_q = (float*)d_out;
  float* out_i = out_q + (size_t)N * D;

  const size_t XB = (size_t)N * 512 * 2;        // xc: 33.5 MB
  const size_t EB = (size_t)K_TOT * 512 * 2;    // ec: 2 MB
  const size_t PB = (size_t)N * 32 * 16;        // p4: 16.8 MB
  const size_t off_ec   = XB;
  const size_t off_p4   = XB + EB;
  const size_t off_esq  = off_p4 + PB;
  const size_t off_list = off_esq + 8192;
  const size_t off_cnt  = off_list + (size_t)N * 4;
  const size_t NEED     = off_cnt + 16;

  char* wsb = (char*)d_ws;

  if (ws_size >= NEED) {
    _Float16* xc   = (_Float16*)wsb;
    _Float16* ec   = (_Float16*)(wsb + off_ec);
    float4*   p4   = (float4*)(wsb + off_p4);
    float*    esq  = (float*)(wsb + off_esq);
    int*      list = (int*)(wsb + off_list);
    int*      cnt  = (int*)(wsb + off_cnt);

    const int NB = N / 4;
    prep_kernel<<<NB + K_TOT / 4 + 1, 256, 0, stream>>>(x, es, usage, xc, ec,
                                                        esq, cnt, NB);
    mm_kernel<<<dim3(16, N / 128), 256, 0, stream>>>(xc, ec, esq, p4, N);
    combine_kernel<<<N / 4, 256, 0, stream>>>(p4, es, usage, out_q, out_i,
                                              list, cnt, N);
    repair_kernel<<<1024, 256, 0, stream>>>(x, es, usage, esq, list, cnt,
                                            out_q, out_i, N);
  } else {
    float* ws    = (float*)d_ws;
    float* esq   = ws;
    float* bestd = ws + K_TOT;
    int*   besti = (int*)(ws + K_TOT + (size_t)KS * N);
    esq_kernel<<<K_TOT / 4, 256, 0, stream>>>(es, usage, esq);
    dist_kernel<<<dim3(N / TN, KS), 256, 0, stream>>>(x, es, usage, esq,
                                                      bestd, besti, N);
    gather_kernel<<<N / 4, 256, 0, stream>>>(es, usage, bestd, besti,
                                             out_q, out_i, N);
  }
}

// Round 6
// 291.454 us; speedup vs baseline: 1.6470x; 1.3379x over previous
//
#include <hip/hip_runtime.h>
#include <float.h>
#include <stdint.h>

// MimiEuclideanCodebook: argmin_k ||x_n - e_k||^2 then gather e_k.
// R6: mm uses double-buffered LDS prefetch (issue stage s+1 loads before
// computing stage s; ONE barrier per stage) and constant-folded staging
// addresses (per-thread base ptr + wave-uniform per-stage offset, fully
// unrolled). Repair is split 8-way per row with packed-u64 atomicMin merge.
// fp16 split-precision MFMA (virtual K=768: xh*eh + xl*eh + xh*el).

#define EPSILON 1e-5f
#define DELTA   1e-3f

constexpr int D     = 256;
constexpr int K_TOT = 2048;

typedef _Float16 half8v __attribute__((ext_vector_type(8)));
typedef _Float16 half4v __attribute__((ext_vector_type(4)));
typedef float    f32x4  __attribute__((ext_vector_type(4)));

// ---------------- fused prep: xc (half+residual), ec, esq, counter ----------------
__global__ void prep_kernel(const float* __restrict__ x,
                            const float* __restrict__ es,
                            const float* __restrict__ usage,
                            _Float16* __restrict__ xc,
                            _Float16* __restrict__ ec,
                            float* __restrict__ esq,
                            int* __restrict__ counter, int NB) {
  const int bx   = blockIdx.x;
  const int t    = threadIdx.x;
  const int wid  = t >> 6;
  const int lane = t & 63;
  if (bx < NB) {                       // x rows: half + residual split
    const int n = bx * 4 + wid;
    const float4 v = *(const float4*)(x + (size_t)n * D + lane * 4);
    half4v h, lo;
    h.x = (_Float16)v.x; lo.x = (_Float16)(v.x - (float)h.x);
    h.y = (_Float16)v.y; lo.y = (_Float16)(v.y - (float)h.y);
    h.z = (_Float16)v.z; lo.z = (_Float16)(v.z - (float)h.z);
    h.w = (_Float16)v.w; lo.w = (_Float16)(v.w - (float)h.w);
    *(half4v*)(xc + (size_t)n * 512 + lane * 4)       = h;
    *(half4v*)(xc + (size_t)n * 512 + 256 + lane * 4) = lo;
  } else if (bx < NB + K_TOT / 4) {    // e rows: divide, split, and esq
    const int k = (bx - NB) * 4 + wid;
    const float u = fmaxf(usage[k], EPSILON);
    const float4 v = *(const float4*)(es + (size_t)k * D + lane * 4);
    float4 e;
    e.x = v.x / u; e.y = v.y / u; e.z = v.z / u; e.w = v.w / u;  // exact div
    half4v h, lo;
    h.x = (_Float16)e.x; lo.x = (_Float16)(e.x - (float)h.x);
    h.y = (_Float16)e.y; lo.y = (_Float16)(e.y - (float)h.y);
    h.z = (_Float16)e.z; lo.z = (_Float16)(e.z - (float)h.z);
    h.w = (_Float16)e.w; lo.w = (_Float16)(e.w - (float)h.w);
    *(half4v*)(ec + (size_t)k * 512 + lane * 4)       = h;
    *(half4v*)(ec + (size_t)k * 512 + 256 + lane * 4) = lo;
    float s = e.x * e.x + e.y * e.y + e.z * e.z + e.w * e.w;
    #pragma unroll
    for (int m = 1; m < 64; m <<= 1) s += __shfl_xor(s, m, 64);
    if (lane == 0) esq[k] = s;
  } else {
    if (t == 0) *counter = 0;
  }
}

// ---------------- MFMA distance GEMM + per-tile top-2 ----------------
// Block tile 128(n) x 128(k); 4 waves (wn,wk in 2x2), each 64x64 with 4x4
// 16x16x32 f16 accs. Grid (16 k-blocks, N/128). Virtual K=768 in 12 BK=64
// stages; stage s covers chunks ka=2s,2s+1; ka 0-7: xh*eh, 8-15: xl*eh,
// 16-23: xh*el. LDS 16B chunks XOR-swizzled (phys = log^(row&7)), so the
// b-dependence (b=chl>>2) folds into the per-thread BASE pointer and the
// per-stage offset is wave-uniform: offA(s)=(s<8?2s:2s-16)*32 halves,
// offB(s)=(s<4?2s:2s-8)*32 halves -> fully unrolled, backend folds to imm.
// Double-buffered LDS: issue s+1 loads into the other buffer BEFORE the
// compute of s, one barrier per stage -> loads fly during the MFMA phase.
__global__ __launch_bounds__(256)
void mm_kernel(const _Float16* __restrict__ xc, const _Float16* __restrict__ ec,
               const float* __restrict__ esq, float4* __restrict__ p4, int N) {
  __shared__ __align__(16) _Float16 sA[2][128 * 64];
  __shared__ __align__(16) _Float16 sB[2][128 * 64];
  const int t    = threadIdx.x;
  const int lane = t & 63;
  const int q    = lane >> 4;
  const int l7   = lane & 7;
  const int wid  = t >> 6;
  const int wn   = wid >> 1;
  const int wk   = wid & 1;
  const int n0   = blockIdx.y * 128;
  const int k0   = blockIdx.x * 128;

  // Per-thread staging descriptors (4 16B slots each for A and B).
  const _Float16* gA[4];
  const _Float16* gB[4];
  int ld[4];
  #pragma unroll
  for (int i = 0; i < 4; ++i) {
    const int p   = i * 256 + t;       // 16B slot 0..1023
    const int row = p >> 3;
    const int chl = (p & 7) ^ (row & 7);   // logical chunk this slot holds
    const int b   = chl >> 2;              // ka parity bit
    const int pc  = chl & 3;               // 16B piece within 32-chunk
    gA[i] = xc + (size_t)(n0 + row) * 512 + b * 32 + pc * 8;
    gB[i] = ec + (size_t)(k0 + row) * 512 + b * 32 + pc * 8;
    ld[i] = p * 8;
  }
  // Fragment-read offsets (loop-invariant).
  int ar[4], br[4], ch[2];
  #pragma unroll
  for (int mi = 0; mi < 4; ++mi) ar[mi] = (wn * 64 + mi * 16 + (lane & 15)) * 64;
  #pragma unroll
  for (int ni = 0; ni < 4; ++ni) br[ni] = (wk * 64 + ni * 16 + (lane & 15)) * 64;
  ch[0] = ((0 * 4 + q) ^ l7) * 8;
  ch[1] = ((1 * 4 + q) ^ l7) * 8;

  f32x4 acc[4][4] = {};

  // Preload stage 0 into buffer 0 (offsets are 0).
  #pragma unroll
  for (int i = 0; i < 4; ++i) {
    __builtin_amdgcn_global_load_lds(
        (const __attribute__((address_space(1))) void*)gA[i],
        (__attribute__((address_space(3))) void*)&sA[0][ld[i]], 16, 0, 0);
    __builtin_amdgcn_global_load_lds(
        (const __attribute__((address_space(1))) void*)gB[i],
        (__attribute__((address_space(3))) void*)&sB[0][ld[i]], 16, 0, 0);
  }
  __syncthreads();

  #pragma unroll
  for (int s = 0; s < 12; ++s) {
    const int cur = s & 1;
    if (s < 11) {
      const int sn = s + 1;
      const int oA = (sn < 8 ? 2 * sn : 2 * sn - 16) * 32;  // halves
      const int oB = (sn < 4 ? 2 * sn : 2 * sn - 8) * 32;
      const int nxt = cur ^ 1;
      #pragma unroll
      for (int i = 0; i < 4; ++i) {
        __builtin_amdgcn_global_load_lds(
            (const __attribute__((address_space(1))) void*)(gA[i] + oA),
            (__attribute__((address_space(3))) void*)&sA[nxt][ld[i]], 16, 0, 0);
        __builtin_amdgcn_global_load_lds(
            (const __attribute__((address_space(1))) void*)(gB[i] + oB),
            (__attribute__((address_space(3))) void*)&sB[nxt][ld[i]], 16, 0, 0);
      }
    }
    #pragma unroll
    for (int s2 = 0; s2 < 2; ++s2) {
      half8v af[4], bf[4];
      #pragma unroll
      for (int mi = 0; mi < 4; ++mi)
        af[mi] = *(const half8v*)&sA[cur][ar[mi] + ch[s2]];
      #pragma unroll
      for (int ni = 0; ni < 4; ++ni)
        bf[ni] = *(const half8v*)&sB[cur][br[ni] + ch[s2]];
      #pragma unroll
      for (int mi = 0; mi < 4; ++mi)
        #pragma unroll
        for (int ni = 0; ni < 4; ++ni)
          acc[mi][ni] = __builtin_amdgcn_mfma_f32_16x16x32_f16(
              af[mi], bf[ni], acc[mi][ni], 0, 0, 0);
    }
    __syncthreads();   // drains this stage's prefetch; syncs LDS reuse
  }

  // Epilogue: dist = esq - 2*dot; top-2 over this wave's 64 k cols.
  // C layout: col = lane&15, row = (lane>>4)*4 + r within each 16-row block.
  float eqv[4];
  int   kc[4];
  #pragma unroll
  for (int ni = 0; ni < 4; ++ni) {
    kc[ni]  = k0 + wk * 64 + ni * 16 + (lane & 15);
    eqv[ni] = esq[kc[ni]];
  }
  const int pt = blockIdx.x * 2 + wk;   // partial slot 0..31, ascending in k
  #pragma unroll
  for (int mi = 0; mi < 4; ++mi) {
    #pragma unroll
    for (int r = 0; r < 4; ++r) {
      float d0 = FLT_MAX, d1 = FLT_MAX;
      int   i0 = 0x7fffffff;
      #pragma unroll
      for (int ni = 0; ni < 4; ++ni) {
        const float d = fmaf(-2.f, acc[mi][ni][r], eqv[ni]);
        if (d < d0) { d1 = d0; d0 = d; i0 = kc[ni]; }
        else if (d < d1) { d1 = d; }
      }
      #pragma unroll
      for (int off = 1; off < 16; off <<= 1) {
        const float od0 = __shfl_xor(d0, off, 16);
        const int   oi0 = __shfl_xor(i0, off, 16);
        const float od1 = __shfl_xor(d1, off, 16);
        if (od0 < d0 || (od0 == d0 && oi0 < i0)) {
          d1 = fminf(d0, od1); d0 = od0; i0 = oi0;
        } else {
          d1 = fminf(d1, od0);
        }
      }
      if ((lane & 15) == mi * 4 + r) {
        const int n = n0 + wn * 64 + mi * 16 + (lane >> 4) * 4 + r;
        p4[(size_t)n * 32 + pt] = make_float4(d0, __int_as_float(i0), d1, 0.f);
      }
    }
  }
}

// ---------------- combine partials + gather + flag ----------------
__global__ void combine_kernel(const float4* __restrict__ p4,
                               const float* __restrict__ es,
                               const float* __restrict__ usage,
                               float* __restrict__ out_q,
                               float* __restrict__ out_i,
                               int* __restrict__ list,
                               int* __restrict__ counter,
                               unsigned long long* __restrict__ rmin, int N) {
  const int wid  = threadIdx.x >> 6;
  const int lane = threadIdx.x & 63;
  const int n    = blockIdx.x * 4 + wid;

  float d0 = FLT_MAX, d1 = FLT_MAX;
  int   i0 = 0x7fffffff;
  if (lane < 32) {
    const float4 pv = p4[(size_t)n * 32 + lane];
    d0 = pv.x; i0 = __float_as_int(pv.y); d1 = pv.z;
  }
  #pragma unroll
  for (int off = 1; off < 64; off <<= 1) {
    const float od0 = __shfl_xor(d0, off, 64);
    const int   oi0 = __shfl_xor(i0, off, 64);
    const float od1 = __shfl_xor(d1, off, 64);
    if (od0 < d0 || (od0 == d0 && oi0 < i0)) {
      d1 = fminf(d0, od1); d0 = od0; i0 = oi0;
    } else {
      d1 = fminf(d1, od0);
    }
  }
  const int idx = i0;
  const float u = fmaxf(usage[idx], EPSILON);
  const float4 e = *(const float4*)(es + (size_t)idx * D + lane * 4);
  float4 qv;
  qv.x = e.x / u; qv.y = e.y / u; qv.z = e.z / u; qv.w = e.w / u;  // exact div
  *(float4*)(out_q + (size_t)n * D + lane * 4) = qv;
  if (lane == 0) {
    out_i[n] = (float)idx;
    if (d1 - d0 < DELTA) {
      rmin[n] = 0xFFFFFFFFFFFFFFFFull;        // init BEFORE repair's atomics
      const int pos = atomicAdd(counter, 1);
      list[pos] = n;
    }
  }
}

// ---------------- exact fp32 repair: 8 blocks per flagged row ----------------
// Block b handles row list[b>>3], codes [ (b&7)*256, (b&7)*256+256 );
// per-wave 64 codes (4-wide ILP); merged via packed-u64 atomicMin
// (monotone float->u32 map in high bits, idx low -> min dist, min idx tie).
__global__ void repair_kernel(const float* __restrict__ x,
                              const float* __restrict__ es,
                              const float* __restrict__ usage,
                              const float* __restrict__ esq,
                              const int* __restrict__ list,
                              const int* __restrict__ counter,
                              unsigned long long* __restrict__ rmin) {
  __shared__ float xs[256];
  const int t    = threadIdx.x;
  const int w    = t >> 6;
  const int lane = t & 63;
  const int cnt  = *counter;
  const int kseg = blockIdx.x & 7;

  for (int j = blockIdx.x >> 3; j < cnt; j += 256) {
    const int n = list[j];
    __syncthreads();
    xs[t] = x[(size_t)n * D + t];
    __syncthreads();
    const float4 xv = *(const float4*)&xs[lane * 4];

    float bd = FLT_MAX;
    int   bi = 0x7fffffff;
    const int kb0 = kseg * 256 + w * 64;
    for (int kk = 0; kk < 64; kk += 4) {
      const int kbase = kb0 + kk;          // ascending within wave
      float pd[4];
      #pragma unroll
      for (int j2 = 0; j2 < 4; ++j2) {
        const int k = kbase + j2;
        const float rs = 1.0f / fmaxf(usage[k], EPSILON);
        const float4 e = *(const float4*)(es + (size_t)k * D + lane * 4);
        float p = xv.x * (e.x * rs);
        p = fmaf(xv.y, e.y * rs, p);
        p = fmaf(xv.z, e.z * rs, p);
        pd[j2] = fmaf(xv.w, e.w * rs, p);
      }
      #pragma unroll
      for (int off = 1; off < 64; off <<= 1) {   // 4 independent chains
        pd[0] += __shfl_xor(pd[0], off, 64);
        pd[1] += __shfl_xor(pd[1], off, 64);
        pd[2] += __shfl_xor(pd[2], off, 64);
        pd[3] += __shfl_xor(pd[3], off, 64);
      }
      #pragma unroll
      for (int j2 = 0; j2 < 4; ++j2) {
        const float dst = fmaf(-2.f, pd[j2], esq[kbase + j2]);
        if (dst < bd) { bd = dst; bi = kbase + j2; }
      }
    }
    if (lane == 0) {
      uint32_t ub = __float_as_uint(bd);
      ub = (ub & 0x80000000u) ? ~ub : (ub | 0x80000000u);
      const unsigned long long pk =
          ((unsigned long long)ub << 32) | (unsigned)bi;
      atomicMin(&rmin[n], pk);
    }
  }
}

// ---------------- repair pass 2: write repaired rows ----------------
__global__ void repair2_kernel(const float* __restrict__ es,
                               const float* __restrict__ usage,
                               const int* __restrict__ list,
                               const int* __restrict__ counter,
                               const unsigned long long* __restrict__ rmin,
                               float* __restrict__ out_q,
                               float* __restrict__ out_i) {
  const int t   = threadIdx.x;
  const int cnt = *counter;
  for (int j = blockIdx.x; j < cnt; j += 1024) {
    const int n   = list[j];
    const int idx = (int)(rmin[n] & 0x7fffffffu);
    const float u = fmaxf(usage[idx], EPSILON);
    out_q[(size_t)n * D + t] = es[(size_t)idx * D + t] / u;   // exact div
    if (t == 0) out_i[n] = (float)idx;
  }
}

// ---------------- fallback path (R1, fp32 vector) ----------------
constexpr int TN = 128;
constexpr int DC = 32;
constexpr int KS = 2;
constexpr int RS = 196;

__global__ void esq_kernel(const float* __restrict__ es,
                           const float* __restrict__ usage,
                           float* __restrict__ esq) {
  const int lane = threadIdx.x & 63;
  const int w    = threadIdx.x >> 6;
  const int k    = blockIdx.x * 4 + w;
  const float u  = fmaxf(usage[k], EPSILON);
  const float4 e = *(const float4*)(es + (size_t)k * D + lane * 4);
  const float a = e.x / u, b = e.y / u, c = e.z / u, d = e.w / u;
  float s = a * a + b * b + c * c + d * d;
  #pragma unroll
  for (int m = 1; m < 64; m <<= 1) s += __shfl_xor(s, m, 64);
  if (lane == 0) esq[k] = s;
}

__global__ __launch_bounds__(256, 2)
void dist_kernel(const float* __restrict__ x,
                 const float* __restrict__ es,
                 const float* __restrict__ usage,
                 const float* __restrict__ esq,
                 float* __restrict__ bestd,
                 int* __restrict__ besti, int N) {
  __shared__ float smX[DC * RS];
  __shared__ float smE[DC * RS];
  const int t    = threadIdx.x;
  const int tx   = t & 15;
  const int ty   = t >> 4;
  const int n0   = blockIdx.x * TN;
  const int half = blockIdx.y;

  float best[8];
  int   bidx[8];
  #pragma unroll
  for (int i = 0; i < 8; ++i) { best[i] = FLT_MAX; bidx[i] = 0; }

  for (int kt = 0; kt < (K_TOT / KS) / 128; ++kt) {
    const int k0 = half * (K_TOT / KS) + kt * 128;
    float acc[8][8];
    #pragma unroll
    for (int i = 0; i < 8; ++i)
      #pragma unroll
      for (int j = 0; j < 8; ++j) acc[i][j] = 0.f;

    for (int dc = 0; dc < D; dc += DC) {
      __syncthreads();
      #pragma unroll
      for (int i = 0; i < 4; ++i) {
        const int f    = i * 256 + t;
        const int row  = f >> 3;
        const int c4   = f & 7;
        const int pcol = row + ((row >> 3) << 2);
        const float4 xv =
            *(const float4*)(x + (size_t)(n0 + row) * D + dc + c4 * 4);
        smX[(c4 * 4 + 0) * RS + pcol] = xv.x;
        smX[(c4 * 4 + 1) * RS + pcol] = xv.y;
        smX[(c4 * 4 + 2) * RS + pcol] = xv.z;
        smX[(c4 * 4 + 3) * RS + pcol] = xv.w;
        const int kk = k0 + row;
        const float rs = 1.0f / fmaxf(usage[kk], EPSILON);
        const float4 ev =
            *(const float4*)(es + (size_t)kk * D + dc + c4 * 4);
        smE[(c4 * 4 + 0) * RS + pcol] = ev.x * rs;
        smE[(c4 * 4 + 1) * RS + pcol] = ev.y * rs;
        smE[(c4 * 4 + 2) * RS + pcol] = ev.z * rs;
        smE[(c4 * 4 + 3) * RS + pcol] = ev.w * rs;
      }
      __syncthreads();
      #pragma unroll 4
      for (int d = 0; d < DC; ++d) {
        const float* px = &smX[d * RS + ty * 12];
        const float* pe = &smE[d * RS + tx * 12];
        const float4 xa = *(const float4*)px;
        const float4 xb = *(const float4*)(px + 4);
        const float4 ea = *(const float4*)pe;
        const float4 eb = *(const float4*)(pe + 4);
        const float xr[8] = {xa.x, xa.y, xa.z, xa.w, xb.x, xb.y, xb.z, xb.w};
        const float er[8] = {ea.x, ea.y, ea.z, ea.w, eb.x, eb.y, eb.z, eb.w};
        #pragma unroll
        for (int i = 0; i < 8; ++i)
          #pragma unroll
          for (int jj = 0; jj < 8; ++jj)
            acc[i][jj] = fmaf(xr[i], er[jj], acc[i][jj]);
      }
    }
    #pragma unroll
    for (int jj = 0; jj < 8; ++jj) {
      const int k = k0 + tx * 8 + jj;
      const float eq = esq[k];
      #pragma unroll
      for (int i = 0; i < 8; ++i) {
        const float dst = fmaf(-2.0f, acc[i][jj], eq);
        if (dst < best[i]) { best[i] = dst; bidx[i] = k; }
      }
    }
  }
  __syncthreads();
  float* rd = smX;
  int*   ri = (int*)smE;
  #pragma unroll
  for (int i = 0; i < 8; ++i) {
    const int r = ty * 8 + i;
    rd[tx * TN + r] = best[i];
    ri[tx * TN + r] = bidx[i];
  }
  __syncthreads();
  for (int off = 8; off >= 1; off >>= 1) {
    if (tx < off) {
      #pragma unroll
      for (int i = 0; i < 8; ++i) {
        const int r = ty * 8 + i;
        const float da = rd[tx * TN + r], db = rd[(tx + off) * TN + r];
        const int   ia = ri[tx * TN + r], ib = ri[(tx + off) * TN + r];
        if (db < da || (db == da && ib < ia)) {
          rd[tx * TN + r] = db;
          ri[tx * TN + r] = ib;
        }
      }
    }
    __syncthreads();
  }
  if (tx == 0) {
    #pragma unroll
    for (int i = 0; i < 8; ++i) {
      const int r = ty * 8 + i;
      bestd[(size_t)half * N + n0 + r] = rd[r];
      besti[(size_t)half * N + n0 + r] = ri[r];
    }
  }
}

__global__ void gather_kernel(const float* __restrict__ es,
                              const float* __restrict__ usage,
                              const float* __restrict__ bestd,
                              const int* __restrict__ besti,
                              float* __restrict__ out_q,
                              float* __restrict__ out_i, int N) {
  const int w    = threadIdx.x >> 6;
  const int lane = threadIdx.x & 63;
  const int n    = blockIdx.x * 4 + w;
  const float d0 = bestd[n];
  const float d1 = bestd[(size_t)N + n];
  const int   i0 = besti[n];
  const int   i1 = besti[(size_t)N + n];
  const int idx = (d1 < d0) ? i1 : i0;
  const float u = fmaxf(usage[idx], EPSILON);
  const float4 e = *(const float4*)(es + (size_t)idx * D + lane * 4);
  float4 qv;
  qv.x = e.x / u; qv.y = e.y / u; qv.z = e.z / u; qv.w = e.w / u;
  *(float4*)(out_q + (size_t)n * D + lane * 4) = qv;
  if (lane == 0) out_i[n] = (float)idx;
}

// ---------------- launch ----------------
extern "C" void kernel_launch(void* const* d_in, const int* in_sizes, int n_in,
                              void* d_out, int out_size, void* d_ws, size_t ws_size,
                              hipStream_t stream) {
  const float* x     = (const float*)d_in[0];  // [N, 256]
  const float* es    = (const float*)d_in[1];  // [2048, 256]
  const float* usage = (const float*)d_in[2];  // [2048]
  const int N = in_sizes[0] / D;               // 32768

  float* out_q = (float*)d_out;
  float* out_i = out_q + (size_t)N * D;

  const size_t XB = (size_t)N * 512 * 2;        // xc: 33.5 MB
  const size_t EB = (size_t)K_TOT * 512 * 2;    // ec: 2 MB
  const size_t PB = (size_t)N * 32 * 16;        // p4: 16.8 MB
  const size_t off_ec   = XB;
  const size_t off_p4   = XB + EB;
  const size_t off_esq  = off_p4 + PB;
  const size_t off_list = off_esq + 8192;
  const size_t off_cnt  = off_list + (size_t)N * 4;
  const size_t off_rmin = off_cnt + 16;
  const size_t NEED     = off_rmin + (size_t)N * 8;

  char* wsb = (char*)d_ws;

  if (ws_size >= NEED) {
    _Float16* xc   = (_Float16*)wsb;
    _Float16* ec   = (_Float16*)(wsb + off_ec);
    float4*   p4   = (float4*)(wsb + off_p4);
    float*    esq  = (float*)(wsb + off_esq);
    int*      list = (int*)(wsb + off_list);
    int*      cnt  = (int*)(wsb + off_cnt);
    unsigned long long* rmin = (unsigned long long*)(wsb + off_rmin);

    const int NB = N / 4;
    prep_kernel<<<NB + K_TOT / 4 + 1, 256, 0, stream>>>(x, es, usage, xc, ec,
                                                        esq, cnt, NB);
    mm_kernel<<<dim3(16, N / 128), 256, 0, stream>>>(xc, ec, esq, p4, N);
    combine_kernel<<<N / 4, 256, 0, stream>>>(p4, es, usage, out_q, out_i,
                                              list, cnt, rmin, N);
    repair_kernel<<<2048, 256, 0, stream>>>(x, es, usage, esq, list, cnt, rmin);
    repair2_kernel<<<1024, 256, 0, stream>>>(es, usage, list, cnt, rmin,
                                             out_q, out_i);
  } else {
    float* ws    = (float*)d_ws;
    float* esq   = ws;
    float* bestd = ws + K_TOT;
    int*   besti = (int*)(ws + K_TOT + (size_t)KS * N);
    esq_kernel<<<K_TOT / 4, 256, 0, stream>>>(es, usage, esq);
    dist_kernel<<<dim3(N / TN, KS), 256, 0, stream>>>(x, es, usage, esq,
                                                      bestd, besti, N);
    gather_kernel<<<N / 4, 256, 0, stream>>>(es, usage, bestd, besti,
                                             out_q, out_i, N);
  }
}

// Round 8
// 289.000 us; speedup vs baseline: 1.6610x; 1.0085x over previous
//
#include <hip/hip_runtime.h>
#include <float.h>
#include <stdint.h>

// MimiEuclideanCodebook: argmin_k ||x_n - e_k||^2 then gather e_k.
// R8 = R7 with the prefetch-wrap bug fixed: (vs+1)&23 -> proper wrap to 0.
// A-resident mm: one block per 128-row n-tile (grid 256 = 1 block/CU).
// Prologue converts x fp32 -> fp16 head|residual straight into a 128 KB
// LDS-resident A-tile. Main loop: 16 k-tiles x 24 BK=32 stages; only B
// (8 KB/stage) is staged, double-buffered; ec (2 MB) is XCD-L2-resident.
// Split-precision virtual K=768: xh*eh + xl*eh + xh*el. Top-2 carried in
// registers across k-tiles; exact-fp32 repair for rows with gap < DELTA.

#define EPSILON 1e-5f
#define DELTA   1e-3f

constexpr int D     = 256;
constexpr int K_TOT = 2048;

// mm LDS layout (halves): A chunk c (0..63), row r (0..127) at c*1032 + r*8
// (129 16B-slots per chunk-column -> pad breaks write-side conflicts).
// B: BBASE + buf*4096 + (q*128 + r)*8.  Total 74240 halves = 148480 B.
constexpr int APH    = 1032;
constexpr int BBASE  = 64 * APH;        // 66048
constexpr int BBUF   = 4096;
constexpr int LDS_HALVES = BBASE + 2 * BBUF;     // 74240
constexpr int DYN_LDS    = LDS_HALVES * 2;       // 148480 bytes

typedef _Float16 half8v __attribute__((ext_vector_type(8)));
typedef _Float16 half4v __attribute__((ext_vector_type(4)));
typedef float    f32x4  __attribute__((ext_vector_type(4)));

// ---------------- prep: ec (half+residual) + esq + counter ----------------
__global__ void prep_kernel(const float* __restrict__ es,
                            const float* __restrict__ usage,
                            _Float16* __restrict__ ec,
                            float* __restrict__ esq,
                            int* __restrict__ counter) {
  const int bx   = blockIdx.x;
  const int t    = threadIdx.x;
  const int wid  = t >> 6;
  const int lane = t & 63;
  if (bx < K_TOT / 4) {
    const int k = bx * 4 + wid;
    const float u = fmaxf(usage[k], EPSILON);
    const float4 v = *(const float4*)(es + (size_t)k * D + lane * 4);
    float4 e;
    e.x = v.x / u; e.y = v.y / u; e.z = v.z / u; e.w = v.w / u;  // exact div
    half4v h, lo;
    h.x = (_Float16)e.x; lo.x = (_Float16)(e.x - (float)h.x);
    h.y = (_Float16)e.y; lo.y = (_Float16)(e.y - (float)h.y);
    h.z = (_Float16)e.z; lo.z = (_Float16)(e.z - (float)h.z);
    h.w = (_Float16)e.w; lo.w = (_Float16)(e.w - (float)h.w);
    *(half4v*)(ec + (size_t)k * 512 + lane * 4)       = h;
    *(half4v*)(ec + (size_t)k * 512 + 256 + lane * 4) = lo;
    float s = e.x * e.x + e.y * e.y + e.z * e.z + e.w * e.w;
    #pragma unroll
    for (int m = 1; m < 64; m <<= 1) s += __shfl_xor(s, m, 64);
    if (lane == 0) esq[k] = s;
  } else {
    if (t == 0) *counter = 0;
  }
}

// ---------------- A-resident MFMA distance GEMM + running top-2 ----------------
__global__ __launch_bounds__(256, 1)
void mm_kernel(const float* __restrict__ x, const _Float16* __restrict__ ec,
               const float* __restrict__ esq, float4* __restrict__ p4, int N) {
  extern __shared__ __align__(16) _Float16 lds[];
  const int t    = threadIdx.x;
  const int lane = t & 63;
  const int q    = lane >> 4;
  const int wid  = t >> 6;
  const int wn   = wid >> 1;
  const int wk   = wid & 1;
  const int n0   = blockIdx.x * 128;

  // ---- prologue: convert x tile into LDS-resident A (head | residual) ----
  // chunk c<32: head halves of floats [8(c&31), 8(c&31)+8); c>=32: residuals.
  #pragma unroll 4
  for (int i = 0; i < 32; ++i) {
    const int idx = i * 256 + t;
    const int r   = idx >> 6;
    const int c   = idx & 63;
    const float* src = x + (size_t)(n0 + r) * D + (c & 31) * 8;
    const float4 f0 = *(const float4*)src;
    const float4 f1 = *(const float4*)(src + 4);
    const float f[8] = {f0.x, f0.y, f0.z, f0.w, f1.x, f1.y, f1.z, f1.w};
    half8v hv;
    if (c < 32) {
      #pragma unroll
      for (int e = 0; e < 8; ++e) hv[e] = (_Float16)f[e];
    } else {
      #pragma unroll
      for (int e = 0; e < 8; ++e) {
        const _Float16 h = (_Float16)f[e];
        hv[e] = (_Float16)(f[e] - (float)h);
      }
    }
    *(half8v*)&lds[c * APH + r * 8] = hv;
  }

  // ---- B staging descriptors: slot p = i*256+t -> (cB = p>>7, r = p&127) ----
  const _Float16* pB[2];
  #pragma unroll
  for (int i = 0; i < 2; ++i) {
    const int p  = i * 256 + t;
    const int cB = p >> 7;
    const int r  = p & 127;
    pB[i] = ec + (size_t)r * 512 + cB * 8;
  }
  // initial B load: (kt=0, vs=0) into buf 0
  #pragma unroll
  for (int i = 0; i < 2; ++i)
    __builtin_amdgcn_global_load_lds(
        (const __attribute__((address_space(1))) void*)pB[i],
        (__attribute__((address_space(3))) void*)&lds[BBASE + (i * 256 + t) * 8],
        16, 0, 0);
  __syncthreads();

  // fragment row offsets (halves), loop-invariant
  int arow[4], brow[4];
  #pragma unroll
  for (int mi = 0; mi < 4; ++mi) arow[mi] = (wn * 64 + mi * 16 + (lane & 15)) * 8;
  #pragma unroll
  for (int ni = 0; ni < 4; ++ni) brow[ni] = (wk * 64 + ni * 16 + (lane & 15)) * 8;

  float rd0[4][4], rd1[4][4];
  int   ri0[4][4];
  #pragma unroll
  for (int mi = 0; mi < 4; ++mi)
    #pragma unroll
    for (int r = 0; r < 4; ++r) {
      rd0[mi][r] = FLT_MAX; rd1[mi][r] = FLT_MAX; ri0[mi][r] = 0x7fffffff;
    }

  int buf = 0;
  for (int kt = 0; kt < 16; ++kt) {
    const bool last_kt = (kt == 15);
    int   kc[4];
    float eqv[4];
    #pragma unroll
    for (int ni = 0; ni < 4; ++ni) {
      kc[ni]  = kt * 128 + wk * 64 + ni * 16 + (lane & 15);
      eqv[ni] = esq[kc[ni]];
    }

    f32x4 acc[4][4] = {};

    // 24 BK=32 stages. A k-step: vs<16 -> vs (xh 0-7, xl 8-15); vs>=16 -> vs-16 (xh).
    // B k-step: vs<8 -> vs (eh); 8-15 -> vs-8 (eh); 16-23 -> vs-8 (el, halves 256+).
    #pragma unroll
    for (int vs = 0; vs < 24; ++vs) {
      const int nvs = (vs + 1 < 24) ? vs + 1 : 0;       // FIXED: proper wrap
      const int nbs = (nvs < 8) ? nvs : nvs - 8;        // next B k-step
      if (!(last_kt && vs == 23)) {
        const int ko = (vs == 23) ? (128 * 512) : 0;    // next k-tile base
        const int nb = buf ^ 1;
        #pragma unroll
        for (int i = 0; i < 2; ++i)
          __builtin_amdgcn_global_load_lds(
              (const __attribute__((address_space(1))) void*)
                  (pB[i] + nbs * 32 + ko),
              (__attribute__((address_space(3))) void*)
                  &lds[BBASE + nb * BBUF + (i * 256 + t) * 8],
              16, 0, 0);
      }
      const int as = (vs < 16) ? vs : vs - 16;          // A k-step
      half8v af[4], bf[4];
      #pragma unroll
      for (int mi = 0; mi < 4; ++mi)
        af[mi] = *(const half8v*)&lds[(as * 4 + q) * APH + arow[mi]];
      #pragma unroll
      for (int ni = 0; ni < 4; ++ni)
        bf[ni] = *(const half8v*)&lds[BBASE + buf * BBUF + q * 1024 + brow[ni]];
      #pragma unroll
      for (int mi = 0; mi < 4; ++mi)
        #pragma unroll
        for (int ni = 0; ni < 4; ++ni)
          acc[mi][ni] = __builtin_amdgcn_mfma_f32_16x16x32_f16(
              af[mi], bf[ni], acc[mi][ni], 0, 0, 0);
      __syncthreads();
      buf ^= 1;
    }

    // merge this k-tile into running top-2 (ascending k, strict '<')
    #pragma unroll
    for (int ni = 0; ni < 4; ++ni) {
      #pragma unroll
      for (int mi = 0; mi < 4; ++mi) {
        #pragma unroll
        for (int r = 0; r < 4; ++r) {
          const float d = fmaf(-2.f, acc[mi][ni][r], eqv[ni]);
          if (d < rd0[mi][r]) {
            rd1[mi][r] = rd0[mi][r]; rd0[mi][r] = d; ri0[mi][r] = kc[ni];
          } else {
            rd1[mi][r] = fminf(rd1[mi][r], d);
          }
        }
      }
    }
    #pragma unroll
    for (int i = 0; i < 2; ++i) pB[i] += 128 * 512;
  }

  // cross-lane reduce over 16 k-cols; one p4 write per (row, wk)
  #pragma unroll
  for (int mi = 0; mi < 4; ++mi) {
    #pragma unroll
    for (int r = 0; r < 4; ++r) {
      float d0 = rd0[mi][r], d1 = rd1[mi][r];
      int   i0 = ri0[mi][r];
      #pragma unroll
      for (int off = 1; off < 16; off <<= 1) {
        const float od0 = __shfl_xor(d0, off, 16);
        const int   oi0 = __shfl_xor(i0, off, 16);
        const float od1 = __shfl_xor(d1, off, 16);
        if (od0 < d0 || (od0 == d0 && oi0 < i0)) {
          d1 = fminf(d0, od1); d0 = od0; i0 = oi0;
        } else {
          d1 = fminf(d1, od0);
        }
      }
      if ((lane & 15) == mi * 4 + r) {
        const int n = n0 + wn * 64 + mi * 16 + (lane >> 4) * 4 + r;
        p4[(size_t)n * 2 + wk] = make_float4(d0, __int_as_float(i0), d1, 0.f);
      }
    }
  }
}

// ---------------- combine 2 partials + gather + flag ----------------
__global__ void combine_kernel(const float4* __restrict__ p4,
                               const float* __restrict__ es,
                               const float* __restrict__ usage,
                               float* __restrict__ out_q,
                               float* __restrict__ out_i,
                               int* __restrict__ list,
                               int* __restrict__ counter,
                               unsigned long long* __restrict__ rmin, int N) {
  const int wid  = threadIdx.x >> 6;
  const int lane = threadIdx.x & 63;
  const int n    = blockIdx.x * 4 + wid;

  float d0 = FLT_MAX, d1 = FLT_MAX;
  int   i0 = 0x7fffffff;
  if (lane < 2) {
    const float4 pv = p4[(size_t)n * 2 + lane];
    d0 = pv.x; i0 = __float_as_int(pv.y); d1 = pv.z;
  }
  {
    const float od0 = __shfl_xor(d0, 1, 2);
    const int   oi0 = __shfl_xor(i0, 1, 2);
    const float od1 = __shfl_xor(d1, 1, 2);
    if (od0 < d0 || (od0 == d0 && oi0 < i0)) {
      d1 = fminf(d0, od1); d0 = od0; i0 = oi0;
    } else {
      d1 = fminf(d1, od0);
    }
  }
  const int   idx = __shfl(i0, 0, 64);
  const float g0  = __shfl(d0, 0, 64);
  const float g1  = __shfl(d1, 0, 64);

  const float u = fmaxf(usage[idx], EPSILON);
  const float4 e = *(const float4*)(es + (size_t)idx * D + lane * 4);
  float4 qv;
  qv.x = e.x / u; qv.y = e.y / u; qv.z = e.z / u; qv.w = e.w / u;  // exact div
  *(float4*)(out_q + (size_t)n * D + lane * 4) = qv;
  if (lane == 0) {
    out_i[n] = (float)idx;
    if (g1 - g0 < DELTA) {
      rmin[n] = 0xFFFFFFFFFFFFFFFFull;
      const int pos = atomicAdd(counter, 1);
      list[pos] = n;
    }
  }
}

// ---------------- exact fp32 repair: 8 blocks per flagged row ----------------
__global__ void repair_kernel(const float* __restrict__ x,
                              const float* __restrict__ es,
                              const float* __restrict__ usage,
                              const float* __restrict__ esq,
                              const int* __restrict__ list,
                              const int* __restrict__ counter,
                              unsigned long long* __restrict__ rmin) {
  __shared__ float xs[256];
  const int t    = threadIdx.x;
  const int w    = t >> 6;
  const int lane = t & 63;
  const int cnt  = *counter;
  const int kseg = blockIdx.x & 7;

  for (int j = blockIdx.x >> 3; j < cnt; j += 256) {
    const int n = list[j];
    __syncthreads();
    xs[t] = x[(size_t)n * D + t];
    __syncthreads();
    const float4 xv = *(const float4*)&xs[lane * 4];

    float bd = FLT_MAX;
    int   bi = 0x7fffffff;
    const int kb0 = kseg * 256 + w * 64;
    for (int kk = 0; kk < 64; kk += 4) {
      const int kbase = kb0 + kk;
      float pd[4];
      #pragma unroll
      for (int j2 = 0; j2 < 4; ++j2) {
        const int k = kbase + j2;
        const float rs = 1.0f / fmaxf(usage[k], EPSILON);
        const float4 e = *(const float4*)(es + (size_t)k * D + lane * 4);
        float p = xv.x * (e.x * rs);
        p = fmaf(xv.y, e.y * rs, p);
        p = fmaf(xv.z, e.z * rs, p);
        pd[j2] = fmaf(xv.w, e.w * rs, p);
      }
      #pragma unroll
      for (int off = 1; off < 64; off <<= 1) {
        pd[0] += __shfl_xor(pd[0], off, 64);
        pd[1] += __shfl_xor(pd[1], off, 64);
        pd[2] += __shfl_xor(pd[2], off, 64);
        pd[3] += __shfl_xor(pd[3], off, 64);
      }
      #pragma unroll
      for (int j2 = 0; j2 < 4; ++j2) {
        const float dst = fmaf(-2.f, pd[j2], esq[kbase + j2]);
        if (dst < bd) { bd = dst; bi = kbase + j2; }
      }
    }
    if (lane == 0) {
      uint32_t ub = __float_as_uint(bd);
      ub = (ub & 0x80000000u) ? ~ub : (ub | 0x80000000u);
      const unsigned long long pk =
          ((unsigned long long)ub << 32) | (unsigned)bi;
      atomicMin(&rmin[n], pk);
    }
  }
}

// ---------------- repair pass 2: write repaired rows ----------------
__global__ void repair2_kernel(const float* __restrict__ es,
                               const float* __restrict__ usage,
                               const int* __restrict__ list,
                               const int* __restrict__ counter,
                               const unsigned long long* __restrict__ rmin,
                               float* __restrict__ out_q,
                               float* __restrict__ out_i) {
  const int t   = threadIdx.x;
  const int cnt = *counter;
  for (int j = blockIdx.x; j < cnt; j += 1024) {
    const int n   = list[j];
    const int idx = (int)(rmin[n] & 0x7fffffffu);
    const float u = fmaxf(usage[idx], EPSILON);
    out_q[(size_t)n * D + t] = es[(size_t)idx * D + t] / u;
    if (t == 0) out_i[n] = (float)idx;
  }
}

// ---------------- fallback path (R1, fp32 vector) ----------------
constexpr int TN = 128;
constexpr int DC = 32;
constexpr int KS = 2;
constexpr int RS = 196;

__global__ void esq_kernel(const float* __restrict__ es,
                           const float* __restrict__ usage,
                           float* __restrict__ esq) {
  const int lane = threadIdx.x & 63;
  const int w    = threadIdx.x >> 6;
  const int k    = blockIdx.x * 4 + w;
  const float u  = fmaxf(usage[k], EPSILON);
  const float4 e = *(const float4*)(es + (size_t)k * D + lane * 4);
  const float a = e.x / u, b = e.y / u, c = e.z / u, d = e.w / u;
  float s = a * a + b * b + c * c + d * d;
  #pragma unroll
  for (int m = 1; m < 64; m <<= 1) s += __shfl_xor(s, m, 64);
  if (lane == 0) esq[k] = s;
}

__global__ __launch_bounds__(256, 2)
void dist_kernel(const float* __restrict__ x,
                 const float* __restrict__ es,
                 const float* __restrict__ usage,
                 const float* __restrict__ esq,
                 float* __restrict__ bestd,
                 int* __restrict__ besti, int N) {
  __shared__ float smX[DC * RS];
  __shared__ float smE[DC * RS];
  const int t    = threadIdx.x;
  const int tx   = t & 15;
  const int ty   = t >> 4;
  const int n0   = blockIdx.x * TN;
  const int half = blockIdx.y;

  float best[8];
  int   bidx[8];
  #pragma unroll
  for (int i = 0; i < 8; ++i) { best[i] = FLT_MAX; bidx[i] = 0; }

  for (int kt = 0; kt < (K_TOT / KS) / 128; ++kt) {
    const int k0 = half * (K_TOT / KS) + kt * 128;
    float acc[8][8];
    #pragma unroll
    for (int i = 0; i < 8; ++i)
      #pragma unroll
      for (int j = 0; j < 8; ++j) acc[i][j] = 0.f;

    for (int dc = 0; dc < D; dc += DC) {
      __syncthreads();
      #pragma unroll
      for (int i = 0; i < 4; ++i) {
        const int f    = i * 256 + t;
        const int row  = f >> 3;
        const int c4   = f & 7;
        const int pcol = row + ((row >> 3) << 2);
        const float4 xv =
            *(const float4*)(x + (size_t)(n0 + row) * D + dc + c4 * 4);
        smX[(c4 * 4 + 0) * RS + pcol] = xv.x;
        smX[(c4 * 4 + 1) * RS + pcol] = xv.y;
        smX[(c4 * 4 + 2) * RS + pcol] = xv.z;
        smX[(c4 * 4 + 3) * RS + pcol] = xv.w;
        const int kk = k0 + row;
        const float rs = 1.0f / fmaxf(usage[kk], EPSILON);
        const float4 ev =
            *(const float4*)(es + (size_t)kk * D + dc + c4 * 4);
        smE[(c4 * 4 + 0) * RS + pcol] = ev.x * rs;
        smE[(c4 * 4 + 1) * RS + pcol] = ev.y * rs;
        smE[(c4 * 4 + 2) * RS + pcol] = ev.z * rs;
        smE[(c4 * 4 + 3) * RS + pcol] = ev.w * rs;
      }
      __syncthreads();
      #pragma unroll 4
      for (int d = 0; d < DC; ++d) {
        const float* px = &smX[d * RS + ty * 12];
        const float* pe = &smE[d * RS + tx * 12];
        const float4 xa = *(const float4*)px;
        const float4 xb = *(const float4*)(px + 4);
        const float4 ea = *(const float4*)pe;
        const float4 eb = *(const float4*)(pe + 4);
        const float xr[8] = {xa.x, xa.y, xa.z, xa.w, xb.x, xb.y, xb.z, xb.w};
        const float er[8] = {ea.x, ea.y, ea.z, ea.w, eb.x, eb.y, eb.z, eb.w};
        #pragma unroll
        for (int i = 0; i < 8; ++i)
          #pragma unroll
          for (int jj = 0; jj < 8; ++jj)
            acc[i][jj] = fmaf(xr[i], er[jj], acc[i][jj]);
      }
    }
    #pragma unroll
    for (int jj = 0; jj < 8; ++jj) {
      const int k = k0 + tx * 8 + jj;
      const float eq = esq[k];
      #pragma unroll
      for (int i = 0; i < 8; ++i) {
        const float dst = fmaf(-2.0f, acc[i][jj], eq);
        if (dst < best[i]) { best[i] = dst; bidx[i] = k; }
      }
    }
  }
  __syncthreads();
  float* rd = smX;
  int*   ri = (int*)smE;
  #pragma unroll
  for (int i = 0; i < 8; ++i) {
    const int r = ty * 8 + i;
    rd[tx * TN + r] = best[i];
    ri[tx * TN + r] = bidx[i];
  }
  __syncthreads();
  for (int off = 8; off >= 1; off >>= 1) {
    if (tx < off) {
      #pragma unroll
      for (int i = 0; i < 8; ++i) {
        const int r = ty * 8 + i;
        const float da = rd[tx * TN + r], db = rd[(tx + off) * TN + r];
        const int   ia = ri[tx * TN + r], ib = ri[(tx + off) * TN + r];
        if (db < da || (db == da && ib < ia)) {
          rd[tx * TN + r] = db;
          ri[tx * TN + r] = ib;
        }
      }
    }
    __syncthreads();
  }
  if (tx == 0) {
    #pragma unroll
    for (int i = 0; i < 8; ++i) {
      const int r = ty * 8 + i;
      bestd[(size_t)half * N + n0 + r] = rd[r];
      besti[(size_t)half * N + n0 + r] = ri[r];
    }
  }
}

__global__ void gather_kernel(const float* __restrict__ es,
                              const float* __restrict__ usage,
                              const float* __restrict__ bestd,
                              const int* __restrict__ besti,
                              float* __restrict__ out_q,
                              float* __restrict__ out_i, int N) {
  const int w    = threadIdx.x >> 6;
  const int lane = threadIdx.x & 63;
  const int n    = blockIdx.x * 4 + w;
  const float d0 = bestd[n];
  const float d1 = bestd[(size_t)N + n];
  const int   i0 = besti[n];
  const int   i1 = besti[(size_t)N + n];
  const int idx = (d1 < d0) ? i1 : i0;
  const float u = fmaxf(usage[idx], EPSILON);
  const float4 e = *(const float4*)(es + (size_t)idx * D + lane * 4);
  float4 qv;
  qv.x = e.x / u; qv.y = e.y / u; qv.z = e.z / u; qv.w = e.w / u;
  *(float4*)(out_q + (size_t)n * D + lane * 4) = qv;
  if (lane == 0) out_i[n] = (float)idx;
}

// ---------------- launch ----------------
extern "C" void kernel_launch(void* const* d_in, const int* in_sizes, int n_in,
                              void* d_out, int out_size, void* d_ws, size_t ws_size,
                              hipStream_t stream) {
  const float* x     = (const float*)d_in[0];  // [N, 256]
  const float* es    = (const float*)d_in[1];  // [2048, 256]
  const float* usage = (const float*)d_in[2];  // [2048]
  const int N = in_sizes[0] / D;               // 32768

  float* out_q = (float*)d_out;
  float* out_i = out_q + (size_t)N * D;

  const size_t EB = (size_t)K_TOT * 512 * 2;    // ec: 2 MB
  const size_t PB = (size_t)N * 2 * 16;         // p4: 1 MB
  const size_t off_p4   = EB;
  const size_t off_esq  = off_p4 + PB;
  const size_t off_list = off_esq + 8192;
  const size_t off_cnt  = off_list + (size_t)N * 4;
  const size_t off_rmin = off_cnt + 16;
  const size_t NEED     = off_rmin + (size_t)N * 8;

  char* wsb = (char*)d_ws;

  hipError_t attr_ok = hipFuncSetAttribute(
      (const void*)mm_kernel, hipFuncAttributeMaxDynamicSharedMemorySize,
      DYN_LDS);

  if (ws_size >= NEED && attr_ok == hipSuccess && (N % 128) == 0) {
    _Float16* ec   = (_Float16*)wsb;
    float4*   p4   = (float4*)(wsb + off_p4);
    float*    esq  = (float*)(wsb + off_esq);
    int*      list = (int*)(wsb + off_list);
    int*      cnt  = (int*)(wsb + off_cnt);
    unsigned long long* rmin = (unsigned long long*)(wsb + off_rmin);

    prep_kernel<<<K_TOT / 4 + 1, 256, 0, stream>>>(es, usage, ec, esq, cnt);
    mm_kernel<<<N / 128, 256, DYN_LDS, stream>>>(x, ec, esq, p4, N);
    combine_kernel<<<N / 4, 256, 0, stream>>>(p4, es, usage, out_q, out_i,
                                              list, cnt, rmin, N);
    repair_kernel<<<2048, 256, 0, stream>>>(x, es, usage, esq, list, cnt, rmin);
    repair2_kernel<<<1024, 256, 0, stream>>>(es, usage, list, cnt, rmin,
                                             out_q, out_i);
  } else {
    float* ws    = (float*)d_ws;
    float* esq   = ws;
    float* bestd = ws + K_TOT;
    int*   besti = (int*)(ws + K_TOT + (size_t)KS * N);
    esq_kernel<<<K_TOT / 4, 256, 0, stream>>>(es, usage, esq);
    dist_kernel<<<dim3(N / TN, KS), 256, 0, stream>>>(x, es, usage, esq,
                                                      bestd, besti, N);
    gather_kernel<<<N / 4, 256, 0, stream>>>(es, usage, bestd, besti,
                                             out_q, out_i, N);
  }
}